// Round 4
// baseline (210.408 us; speedup 1.0000x reference)
//
#include <hip/hip_runtime.h>
#include <hip/hip_bf16.h>

typedef unsigned short u16;
typedef __bf16 bf16x8 __attribute__((ext_vector_type(8)));
typedef float f32x4 __attribute__((ext_vector_type(4)));

#define MARGIN 0.2f
#define NEG_INF -3.0e38f

__device__ __forceinline__ u16 f2bf_rne(float f) {
  unsigned u = __builtin_bit_cast(unsigned, f);
  u += 0x7FFFu + ((u >> 16) & 1u);
  return (u16)(u >> 16);
}

// ---------------- prep: fp32 -> bf16 + row sum-of-squares (+ fused zero/cvt) ---
// block = 256 threads = 4 rows x 64 lanes; grid = (N/4, 3)
__global__ void prep_kernel(const float* __restrict__ A, const float* __restrict__ P,
                            const float* __restrict__ Ng, const int* __restrict__ tg,
                            u16* __restrict__ Ab, u16* __restrict__ Pb, u16* __restrict__ Nb,
                            float* __restrict__ an, float* __restrict__ pn, float* __restrict__ nn,
                            int* __restrict__ cls, float* __restrict__ out, int D, int N) {
  if (blockIdx.y == 0) {
    if (blockIdx.x == 0 && threadIdx.x == 0) out[0] = 0.f;
    if ((int)blockIdx.x < (N >> 8)) {
      const int i = blockIdx.x * 256 + threadIdx.x;
      cls[i] = tg[i];
    }
  }
  const int row  = blockIdx.x * 4 + (threadIdx.x >> 6);
  const int lane = threadIdx.x & 63;
  const float* src; u16* dst; float* nrm;
  if (blockIdx.y == 0)      { src = A;  dst = Ab; nrm = an; }
  else if (blockIdx.y == 1) { src = P;  dst = Pb; nrm = pn; }
  else                      { src = Ng; dst = Nb; nrm = nn; }
  float4 v = *(const float4*)(src + (size_t)row * D + lane * 4);
  float ss = v.x * v.x + v.y * v.y + v.z * v.z + v.w * v.w;
  ushort4 o = make_ushort4(f2bf_rne(v.x), f2bf_rne(v.y), f2bf_rne(v.z), f2bf_rne(v.w));
  *(ushort4*)(dst + (size_t)row * D + lane * 4) = o;
  #pragma unroll
  for (int m = 1; m < 64; m <<= 1) ss += __shfl_xor(ss, m);
  if (lane == 0) nrm[row] = ss;
}

// ---------------- staging: 256 rows x 64 bf16 of one operand K-tile -> LDS -----
// LDS dest linear (required by global_load_lds); XOR swizzle (slot ^= row&7)
// realized by pre-swizzling the per-lane GLOBAL source (both-sides pairing).
__device__ __forceinline__ void stage_op(const u16* __restrict__ g, int gbase,
                                         u16* lds, int kt, int D, int w, int l) {
  #pragma unroll
  for (int j = 0; j < 4; ++j) {
    const int row = j * 64 + w * 8 + (l >> 3);
    const int src = (l & 7) ^ (row & 7);
    const u16* gp = g + (size_t)(gbase + row) * D + kt * 64 + src * 8;
    u16* lp = lds + j * 4096 + w * 512;   // wave-uniform base; HW adds lane*16B
    __builtin_amdgcn_global_load_lds((const __attribute__((address_space(1))) void*)gp,
                                     (__attribute__((address_space(3))) void*)lp,
                                     16, 0, 0);
  }
}

#define LOAD_A(KK)                                                                 \
  _Pragma("unroll")                                                                \
  for (int m_ = 0; m_ < 8; ++m_) {                                                 \
    const int row_ = wr * 128 + m_ * 16 + lr;                                      \
    a[m_] = *(const bf16x8*)&Ac[row_ * 64 + (((KK) * 4 + g) ^ (row_ & 7)) * 8];    \
  }

#define LOAD_B(DST, NN, KK)                                                        \
  { const int col_ = wc * 64 + (NN) * 16 + lr;                                     \
    DST = *(const bf16x8*)&Bc[col_ * 64 + (((KK) * 4 + g) ^ (col_ & 7)) * 8]; }

#define MFMA_PHASE(NA, NB, BA, BB)                                                 \
  __builtin_amdgcn_s_setprio(1);                                                   \
  _Pragma("unroll")                                                                \
  for (int m_ = 0; m_ < 8; ++m_) {                                                 \
    acc[m_][NA] = __builtin_amdgcn_mfma_f32_16x16x32_bf16(a[m_], BA, acc[m_][NA], 0, 0, 0); \
    acc[m_][NB] = __builtin_amdgcn_mfma_f32_16x16x32_bf16(a[m_], BB, acc[m_][NB], 0, 0, 0); \
  }                                                                                \
  __builtin_amdgcn_s_setprio(0);                                                   \
  __builtin_amdgcn_sched_barrier(0);

// ---------------- main fused kernel: 256x256 tile, 8 waves, sub-phased ---------
// z = 0: P-GEMM -> masked row max partials; z = 1: N-GEMM -> masked row min
// (via -max(-x)). K = 256 = 4 K-tiles of 64; 4 phases/K-tile, 16 MFMA each.
__global__ __launch_bounds__(512, 2) void triplet_gemm_kernel(
    const u16* __restrict__ Ab, const u16* __restrict__ Pb, const u16* __restrict__ Nb,
    const float* __restrict__ pnorm, const float* __restrict__ nnorm,
    const int* __restrict__ cls,
    float* __restrict__ maxP, float* __restrict__ minN, int N, int D) {
  __shared__ __align__(16) u16 bufA[2][256 * 64];   // 2 x 32 KB
  __shared__ __align__(16) u16 bufB[2][256 * 64];   // 2 x 32 KB
  __shared__ float nS[256];
  __shared__ int   ccS[256], rcS[256];
  __shared__ float red[4][256];

  const int cb = blockIdx.x, rb = blockIdx.y, z = blockIdx.z;
  const int rowbase = rb * 256, colbase = cb * 256;
  const u16*  __restrict__ Bmat = z ? Nb : Pb;
  const float* __restrict__ cn  = z ? nnorm : pnorm;
  const float sgn = z ? -1.f : 1.f;

  const int tid = threadIdx.x, l = tid & 63, w = tid >> 6;
  const int wr = w >> 2, wc = w & 3, g = l >> 4, lr = l & 15;

  if (tid < 256) { nS[tid] = cn[colbase + tid]; ccS[tid] = cls[colbase + tid]; }
  else           { rcS[tid - 256] = cls[rowbase + (tid - 256)]; }

  // prologue: stage K-tiles 0 and 1 (16 gload_lds / thread-wave)
  stage_op(Ab,   rowbase, bufA[0], 0, D, w, l);
  stage_op(Bmat, colbase, bufB[0], 0, D, w, l);
  stage_op(Ab,   rowbase, bufA[1], 1, D, w, l);
  stage_op(Bmat, colbase, bufB[1], 1, D, w, l);

  f32x4 acc[8][4];
  #pragma unroll
  for (int m = 0; m < 8; ++m)
    #pragma unroll
    for (int n = 0; n < 4; ++n) acc[m][n] = (f32x4){0.f, 0.f, 0.f, 0.f};

  #pragma unroll
  for (int t = 0; t < 4; ++t) {
    const u16* __restrict__ Ac = bufA[t & 1];
    const u16* __restrict__ Bc = bufB[t & 1];
    // tile entry: own K-tile-t loads drained (issued >=4 phases ago except t=0),
    // barrier makes all waves' contributions visible.
    if (t == 0) { asm volatile("s_waitcnt vmcnt(8)" ::: "memory"); }
    else        { asm volatile("s_waitcnt vmcnt(0)" ::: "memory"); }
    __builtin_amdgcn_s_barrier();

    bf16x8 a[8], b0, b1, b2, b3;
    // ---- phase q0 (kk=0, n-pair {0,1}) + prefetch issue for K-tile t+1
    LOAD_A(0);
    LOAD_B(b0, 0, 0); LOAD_B(b1, 1, 0);
    if (t == 1 || t == 2) {   // tile t+1 -> buf[(t+1)&1]; prior reader (t-1) done
      stage_op(Ab,   rowbase, bufA[(t + 1) & 1], t + 1, D, w, l);
      stage_op(Bmat, colbase, bufB[(t + 1) & 1], t + 1, D, w, l);
    }
    __builtin_amdgcn_s_barrier();
    MFMA_PHASE(0, 1, b0, b1);
    __builtin_amdgcn_s_barrier();
    // ---- phase q1 (kk=0, n-pair {2,3})
    LOAD_B(b2, 2, 0); LOAD_B(b3, 3, 0);
    MFMA_PHASE(2, 3, b2, b3);
    __builtin_amdgcn_s_barrier();
    // ---- phase q2 (kk=1, n-pair {0,1})
    LOAD_A(1);
    LOAD_B(b0, 0, 1); LOAD_B(b1, 1, 1);
    __builtin_amdgcn_s_barrier();
    MFMA_PHASE(0, 1, b0, b1);
    __builtin_amdgcn_s_barrier();
    // ---- phase q3 (kk=1, n-pair {2,3})
    LOAD_B(b2, 2, 1); LOAD_B(b3, 3, 1);
    MFMA_PHASE(2, 3, b2, b3);
    // next tile's entry vmcnt+barrier closes this tile
  }

  // ---- epilogue: masked row reduce on (colnorm - 2*dot)
  // C/D layout: col = lane&15, row = (lane>>4)*4 + reg  [measured m89/m91]
  #pragma unroll
  for (int m = 0; m < 8; ++m) {
    #pragma unroll
    for (int r = 0; r < 4; ++r) {
      const int row = wr * 128 + m * 16 + g * 4 + r;
      const int rc  = rcS[row];
      float v = NEG_INF;
      #pragma unroll
      for (int n = 0; n < 4; ++n) {
        const int col = wc * 64 + n * 16 + lr;
        const bool same = (rc == ccS[col]);
        const bool want = z ? !same : same;
        const float q = sgn * fmaf(-2.f, acc[m][n][r], nS[col]);
        v = want ? fmaxf(v, q) : v;
      }
      #pragma unroll
      for (int msk = 1; msk < 16; msk <<= 1) v = fmaxf(v, __shfl_xor(v, msk));
      if (lr == 0) red[wc][row] = v;
    }
  }
  __syncthreads();
  if (tid < 256) {
    const float v = fmaxf(fmaxf(red[0][tid], red[1][tid]),
                          fmaxf(red[2][tid], red[3][tid]));
    float* __restrict__ outp = z ? minN : maxP;
    outp[(size_t)cb * N + rowbase + tid] = sgn * v;   // z=1: -max(-x) = min(x)
  }
}

// ---------------- finalize: combine partials, loss, mean ----------------------
__global__ void finalize_kernel(const float* __restrict__ maxP, const float* __restrict__ minN,
                                const float* __restrict__ an, float* out, int N, int nCB) {
  const int r = blockIdx.x * 128 + threadIdx.x;
  float mx = NEG_INF, mn = 3.0e38f;
  for (int cb = 0; cb < nCB; ++cb) {
    mx = fmaxf(mx, maxP[(size_t)cb * N + r]);
    mn = fminf(mn, minN[(size_t)cb * N + r]);
  }
  const float a  = an[r];
  const float dp = sqrtf(fmaxf(a + mx, 1e-12f));
  const float dn = sqrtf(fmaxf(a + mn, 1e-12f));
  float loss = fmaxf(dp - dn + MARGIN, 0.f);
  #pragma unroll
  for (int msk = 1; msk < 64; msk <<= 1) loss += __shfl_xor(loss, msk);
  __shared__ float s[2];
  if ((threadIdx.x & 63) == 0) s[threadIdx.x >> 6] = loss;
  __syncthreads();
  if (threadIdx.x == 0) atomicAdd(out, (s[0] + s[1]) * (1.0f / N));
}

extern "C" void kernel_launch(void* const* d_in, const int* in_sizes, int n_in,
                              void* d_out, int out_size, void* d_ws, size_t ws_size,
                              hipStream_t stream) {
  const float* A  = (const float*)d_in[0];
  const float* P  = (const float*)d_in[1];
  const float* Ng = (const float*)d_in[2];
  const int*   tg = (const int*)d_in[3];
  float* out = (float*)d_out;

  const int N = in_sizes[3];        // 8192
  const int D = in_sizes[0] / N;    // 256
  const int nRB = N / 256, nCB = N / 256;

  char* ws = (char*)d_ws;
  const size_t bf = (size_t)N * D * sizeof(u16);
  u16* Ab = (u16*)ws;
  u16* Pb = (u16*)(ws + bf);
  u16* Nb = (u16*)(ws + 2 * bf);
  char* p = ws + 3 * bf;
  float* an = (float*)p; p += (size_t)N * 4;
  float* pn = (float*)p; p += (size_t)N * 4;
  float* nn = (float*)p; p += (size_t)N * 4;
  int*  cls = (int*)p;   p += (size_t)N * 4;
  float* maxP = (float*)p; p += (size_t)nCB * N * 4;
  float* minN = (float*)p;

  prep_kernel<<<dim3(N / 4, 3), 256, 0, stream>>>(A, P, Ng, tg, Ab, Pb, Nb,
                                                  an, pn, nn, cls, out, D, N);
  triplet_gemm_kernel<<<dim3(nCB, nRB, 2), 512, 0, stream>>>(Ab, Pb, Nb, pn, nn, cls,
                                                             maxP, minN, N, D);
  finalize_kernel<<<N / 128, 128, 0, stream>>>(maxP, minN, an, out, N, nCB);
}

// Round 6
// 187.995 us; speedup vs baseline: 1.1192x; 1.1192x over previous
//
#include <hip/hip_runtime.h>
#include <hip/hip_bf16.h>

typedef unsigned short u16;
typedef __bf16 bf16x8 __attribute__((ext_vector_type(8)));
typedef float f32x4 __attribute__((ext_vector_type(4)));

#define MARGIN 0.2f
#define NEG_INF -3.0e38f

__device__ __forceinline__ u16 f2bf_rne(float f) {
  unsigned u = __builtin_bit_cast(unsigned, f);
  u += 0x7FFFu + ((u >> 16) & 1u);
  return (u16)(u >> 16);
}

// ---------------- prep: fp32 -> bf16 + row sum-of-squares (+ fused zero/cvt) ---
// block = 256 threads = 4 rows x 64 lanes; grid = (N/4, 3)
__global__ void prep_kernel(const float* __restrict__ A, const float* __restrict__ P,
                            const float* __restrict__ Ng, const int* __restrict__ tg,
                            u16* __restrict__ Ab, u16* __restrict__ Pb, u16* __restrict__ Nb,
                            float* __restrict__ an, float* __restrict__ pn, float* __restrict__ nn,
                            int* __restrict__ cls, float* __restrict__ out, int D, int N) {
  if (blockIdx.y == 0) {
    if (blockIdx.x == 0 && threadIdx.x == 0) out[0] = 0.f;
    if ((int)blockIdx.x < (N >> 8)) {
      const int i = blockIdx.x * 256 + threadIdx.x;
      cls[i] = tg[i];
    }
  }
  const int row  = blockIdx.x * 4 + (threadIdx.x >> 6);
  const int lane = threadIdx.x & 63;
  const float* src; u16* dst; float* nrm;
  if (blockIdx.y == 0)      { src = A;  dst = Ab; nrm = an; }
  else if (blockIdx.y == 1) { src = P;  dst = Pb; nrm = pn; }
  else                      { src = Ng; dst = Nb; nrm = nn; }
  float4 v = *(const float4*)(src + (size_t)row * D + lane * 4);
  float ss = v.x * v.x + v.y * v.y + v.z * v.z + v.w * v.w;
  ushort4 o = make_ushort4(f2bf_rne(v.x), f2bf_rne(v.y), f2bf_rne(v.z), f2bf_rne(v.w));
  *(ushort4*)(dst + (size_t)row * D + lane * 4) = o;
  #pragma unroll
  for (int m = 1; m < 64; m <<= 1) ss += __shfl_xor(ss, m);
  if (lane == 0) nrm[row] = ss;
}

// ---------------- staging: 128 rows x 64 bf16 of g[rbase..][kb*64..] -> LDS -----
// LDS dest linear (required by global_load_lds); XOR read-swizzle realized by
// pre-swizzling the per-lane GLOBAL source (both-sides-or-neither pairing).
__device__ __forceinline__ void stage_tile(const u16* __restrict__ g, u16* lds,
                                           int rbase, int kb, int D, int w, int l) {
  #pragma unroll
  for (int c = 0; c < 4; ++c) {
    const int row  = w * 32 + c * 8 + (l >> 3);   // 8 lanes cover one 128B row
    const int slot = (l & 7) ^ (row & 7);         // inverse of read-side swizzle
    const u16* gp = g + (size_t)(rbase + row) * D + kb * 64 + slot * 8;
    u16* lp = lds + w * 2048 + c * 512;           // wave-uniform base; HW adds lane*16B
    __builtin_amdgcn_global_load_lds((const __attribute__((address_space(1))) void*)gp,
                                     (__attribute__((address_space(3))) void*)lp,
                                     16, 0, 0);
  }
}

// ---------------- main fused kernel -------------------------------------------
// z-split: z=0 -> A·P^T, masked row-max partials; z=1 -> A·N^T, masked row-min
// (via -max(-x)). 128x128 tile, 4 waves (2x2), K=256 in 4 steps of BK=64.
// Single-buffered, 2 barriers/K-tile; residency target 4 blocks/CU (TLP hides
// the per-tile stage drain — m114 mechanism).
__global__ __launch_bounds__(256, 4) void triplet_tile_kernel(
    const u16* __restrict__ Ab, const u16* __restrict__ Pb, const u16* __restrict__ Nb,
    const float* __restrict__ pnorm, const float* __restrict__ nnorm,
    const int* __restrict__ cls,
    float* __restrict__ maxP, float* __restrict__ minN, int N, int D) {
  __shared__ __align__(16) u16 As[128 * 64];      // 16 KB
  __shared__ __align__(16) u16 Bs[128 * 64];      // 16 KB
  __shared__ float nS[128];
  __shared__ int   ccS[128], rcS[128];
  __shared__ float red[2][128];

  const int cb = blockIdx.x, rb = blockIdx.y, z = blockIdx.z;
  const int rowbase = rb * 128, colbase = cb * 128;
  const u16*  __restrict__ Bmat = z ? Nb : Pb;
  const float* __restrict__ cn  = z ? nnorm : pnorm;
  const float sgn = z ? -1.f : 1.f;

  const int t = threadIdx.x, l = t & 63, w = t >> 6;
  const int wr = w >> 1, wc = w & 1, g = l >> 4, lr = l & 15;

  if (t < 128) {
    nS[t]  = cn[colbase + t];
    ccS[t] = cls[colbase + t];
  } else {
    rcS[t - 128] = cls[rowbase + (t - 128)];
  }

  f32x4 acc[4][4];
  #pragma unroll
  for (int m = 0; m < 4; ++m)
    #pragma unroll
    for (int n = 0; n < 4; ++n) acc[m][n] = (f32x4){0.f, 0.f, 0.f, 0.f};

  const int nKB = D / 64;
  for (int kb = 0; kb < nKB; ++kb) {
    __syncthreads();                       // previous tile fully consumed
    stage_tile(Ab,   As, rowbase, kb, D, w, l);
    stage_tile(Bmat, Bs, colbase, kb, D, w, l);
    __syncthreads();                       // drains vmcnt -> LDS data visible
    #pragma unroll
    for (int kk = 0; kk < 2; ++kk) {
      bf16x8 af[4], bf[4];
      #pragma unroll
      for (int m = 0; m < 4; ++m) {
        const int row  = wr * 64 + m * 16 + lr;
        const int slot = (kk * 4 + g) ^ (row & 7);
        af[m] = *(const bf16x8*)&As[row * 64 + slot * 8];
      }
      #pragma unroll
      for (int n = 0; n < 4; ++n) {
        const int col  = wc * 64 + n * 16 + lr;
        const int slot = (kk * 4 + g) ^ (col & 7);
        bf[n] = *(const bf16x8*)&Bs[col * 64 + slot * 8];
      }
      #pragma unroll
      for (int m = 0; m < 4; ++m)
        #pragma unroll
        for (int n = 0; n < 4; ++n)
          acc[m][n] = __builtin_amdgcn_mfma_f32_16x16x32_bf16(af[m], bf[n], acc[m][n], 0, 0, 0);
    }
  }

  // Epilogue: masked row reduce on sgn*(colnorm - 2*dot); C/D layout:
  // col = lane&15, row = (lane>>4)*4 + reg  [measured m89/m91]
  #pragma unroll
  for (int m = 0; m < 4; ++m) {
    #pragma unroll
    for (int r = 0; r < 4; ++r) {
      const int row = wr * 64 + m * 16 + g * 4 + r;
      const int rc  = rcS[row];
      float v = NEG_INF;
      #pragma unroll
      for (int n = 0; n < 4; ++n) {
        const int col = wc * 64 + n * 16 + lr;
        const bool same = (rc == ccS[col]);
        const bool want = z ? !same : same;
        const float q = sgn * fmaf(-2.f, acc[m][n][r], nS[col]);
        v = want ? fmaxf(v, q) : v;
      }
      #pragma unroll
      for (int msk = 1; msk < 16; msk <<= 1) v = fmaxf(v, __shfl_xor(v, msk));
      if (lr == 0) red[wc][row] = v;
    }
  }
  __syncthreads();
  if (t < 128) {
    const float v = fmaxf(red[0][t], red[1][t]);
    float* __restrict__ outp = z ? minN : maxP;
    outp[(size_t)cb * N + rowbase + t] = sgn * v;   // z=1: -max(-x) = min(x)
  }
}

// ---------------- finalize: combine partials, loss, mean ----------------------
__global__ void finalize_kernel(const float* __restrict__ maxP, const float* __restrict__ minN,
                                const float* __restrict__ an, float* out, int N, int nCB) {
  const int r = blockIdx.x * 128 + threadIdx.x;
  float mx = NEG_INF, mn = 3.0e38f;
  for (int cb = 0; cb < nCB; ++cb) {
    mx = fmaxf(mx, maxP[(size_t)cb * N + r]);
    mn = fminf(mn, minN[(size_t)cb * N + r]);
  }
  const float a  = an[r];
  const float dp = sqrtf(fmaxf(a + mx, 1e-12f));
  const float dn = sqrtf(fmaxf(a + mn, 1e-12f));
  float loss = fmaxf(dp - dn + MARGIN, 0.f);
  #pragma unroll
  for (int msk = 1; msk < 64; msk <<= 1) loss += __shfl_xor(loss, msk);
  __shared__ float s[2];
  if ((threadIdx.x & 63) == 0) s[threadIdx.x >> 6] = loss;
  __syncthreads();
  if (threadIdx.x == 0) atomicAdd(out, (s[0] + s[1]) * (1.0f / N));
}

extern "C" void kernel_launch(void* const* d_in, const int* in_sizes, int n_in,
                              void* d_out, int out_size, void* d_ws, size_t ws_size,
                              hipStream_t stream) {
  const float* A  = (const float*)d_in[0];
  const float* P  = (const float*)d_in[1];
  const float* Ng = (const float*)d_in[2];
  const int*   tg = (const int*)d_in[3];
  float* out = (float*)d_out;

  const int N = in_sizes[3];        // 8192
  const int D = in_sizes[0] / N;    // 256
  const int nRB = N / 128, nCB = N / 128;

  char* ws = (char*)d_ws;
  const size_t bf = (size_t)N * D * sizeof(u16);
  u16* Ab = (u16*)ws;
  u16* Pb = (u16*)(ws + bf);
  u16* Nb = (u16*)(ws + 2 * bf);
  char* p = ws + 3 * bf;
  float* an = (float*)p; p += (size_t)N * 4;
  float* pn = (float*)p; p += (size_t)N * 4;
  float* nn = (float*)p; p += (size_t)N * 4;
  int*  cls = (int*)p;   p += (size_t)N * 4;
  float* maxP = (float*)p; p += (size_t)nCB * N * 4;
  float* minN = (float*)p;

  prep_kernel<<<dim3(N / 4, 3), 256, 0, stream>>>(A, P, Ng, tg, Ab, Pb, Nb,
                                                  an, pn, nn, cls, out, D, N);
  triplet_tile_kernel<<<dim3(nCB, nRB, 2), 256, 0, stream>>>(Ab, Pb, Nb, pn, nn, cls,
                                                             maxP, minN, N, D);
  finalize_kernel<<<N / 128, 128, 0, stream>>>(maxP, minN, an, out, N, nCB);
}